// Round 10
// baseline (220.583 us; speedup 1.0000x reference)
//
#include <hip/hip_runtime.h>

using u16 = unsigned short;
using short4v = __attribute__((ext_vector_type(4))) short;
using short8 = __attribute__((ext_vector_type(8))) short;
using floatx4 = __attribute__((ext_vector_type(4))) float;

__device__ __forceinline__ float bf2f(u16 h) {
  union { unsigned int u; float f; } v;
  v.u = ((unsigned int)h) << 16;
  return v.f;
}
__device__ __forceinline__ u16 f2bf(float f) {
  union { float f; unsigned int u; } v;
  v.f = f;
  unsigned int u = v.u;
  return (u16)((u + 0x7FFFu + ((u >> 16) & 1u)) >> 16);
}
__device__ __forceinline__ u16 f2bf_rtz(float f) {  // truncate: 1 op
  union { float f; unsigned int u; } v;
  v.f = f;
  return (u16)(v.u >> 16);
}

// async global->LDS 16B copy (dest must be uniform base + lane*16)
typedef const __attribute__((address_space(1))) unsigned int* gas_t;
typedef __attribute__((address_space(3))) unsigned int* las_t;
__device__ __forceinline__ void gl_lds16(const u16* g, u16* l) {
  __builtin_amdgcn_global_load_lds((gas_t)(const void*)g, (las_t)(void*)l, 16,
                                   0, 0);
}

// Q prescale: 0.125 (hd^-0.5) * log2(e), so scores come out in log2 domain
#define QSCALE 0.180336880111f
#define EXPBIAS 23.0831206542f  // 16 * log2(e)

// ---------------------------------------------------------------------------
// All f32 -> bf16 conversions in ONE launch.
// ---------------------------------------------------------------------------
__global__ __launch_bounds__(256) void cvt_all(
    const float* __restrict__ x, const float* __restrict__ wq,
    const float* __restrict__ wp, u16* __restrict__ xb, u16* __restrict__ wqb,
    u16* __restrict__ wpb) {
  int i = blockIdx.x * 256 + threadIdx.x;
  const float* src;
  u16* dst;
  int off;
  if (i < 1048576) {
    src = x; dst = xb; off = i;
  } else if (i < 1048576 + 786432) {
    src = wq; dst = wqb; off = i - 1048576;
  } else {
    src = wp; dst = wpb; off = i - 1835008;
  }
  float4 v = ((const float4*)src)[off];
  ushort4 o;
  o.x = f2bf(v.x);
  o.y = f2bf(v.y);
  o.z = f2bf(v.z);
  o.w = f2bf(v.w);
  ((ushort4*)dst)[off] = o;
}

// ---------------------------------------------------------------------------
// Fused QKV GEMM + rmsnorm + rotary (Q,K) + compact V emit.
// m97 structure: 128x128 block tile, BK=32, global_load_lds staging, 4 waves
// in 2x2, wave tile 64x64 = one full head per wave (64 tokens x 64 ch).
// blockIdx.x 0..7 = Q channels, 8..15 = K, 16..23 = V.
// Q/K epilogue: rmsnorm over the 16-lane col group (4 regs + 4-hop shfl),
// rope pair via shfl_xor(v,1) (bit0 of d == bit0 of lane), write Qb/Kb
// [bh][n][d] bf16 (Q pre-scaled by QSCALE). V: compact Vraw[t][1024] bf16.
// ---------------------------------------------------------------------------
__global__ __launch_bounds__(256) void gemm_qkv(
    const u16* __restrict__ A, const u16* __restrict__ B,
    const float* __restrict__ qw, const float* __restrict__ kw,
    const float* __restrict__ pcos, const float* __restrict__ psin,
    u16* __restrict__ Qb, u16* __restrict__ Kb, u16* __restrict__ Vraw) {
  __shared__ u16 As[128 * 32];
  __shared__ u16 Bs[128 * 32];
  const int tid = threadIdx.x;
  const int lane = tid & 63;
  const int wave = tid >> 6;
  const int col = lane & 15;
  const int quad = lane >> 4;
  const int bm = blockIdx.y * 128;
  const int bn = blockIdx.x * 128;
  const int wm = (wave >> 1) * 64;
  const int wn = (wave & 1) * 64;
  const int K = 1024;

  floatx4 acc[4][4] = {};

  for (int kb = 0; kb < K; kb += 32) {
    __syncthreads();
#pragma unroll
    for (int i = 0; i < 2; i++) {
      const int c = i * 256 + tid;
      const int row = c >> 2;
      const int kc = (c & 3) * 8;
      gl_lds16(A + (size_t)(bm + row) * K + kb + kc, As + c * 8);
      gl_lds16(B + (size_t)(bn + row) * K + kb + kc, Bs + c * 8);
    }
    __syncthreads();

    short8 af[4], bfr[4];
#pragma unroll
    for (int i = 0; i < 4; i++)
      af[i] = *(const short8*)(As + (wm + i * 16 + col) * 32 + quad * 8);
#pragma unroll
    for (int i = 0; i < 4; i++)
      bfr[i] = *(const short8*)(Bs + (wn + i * 16 + col) * 32 + quad * 8);
#pragma unroll
    for (int mi = 0; mi < 4; mi++)
#pragma unroll
      for (int ni = 0; ni < 4; ni++)
        acc[mi][ni] = __builtin_amdgcn_mfma_f32_16x16x32_bf16(
            af[mi], bfr[ni], acc[mi][ni], 0, 0, 0);
  }

  const int region = (int)blockIdx.x >> 3;  // 0=Q, 1=K, 2=V (block-uniform)

  if (region == 2) {
    const int c0 = ((int)blockIdx.x - 16) * 128 + wn;
#pragma unroll
    for (int mi = 0; mi < 4; mi++)
#pragma unroll
      for (int ni = 0; ni < 4; ni++)
#pragma unroll
        for (int r = 0; r < 4; r++) {
          int row = bm + wm + mi * 16 + quad * 4 + r;
          Vraw[(size_t)row * 1024 + c0 + ni * 16 + col] = f2bf(acc[mi][ni][r]);
        }
  } else {
    const float* w = region ? kw : qw;
    u16* Out = region ? Kb : Qb;
    const int hh = (((int)blockIdx.x & 7) * 128 + wn) >> 6;  // head 0..15
    const int bb = bm >> 11;
    const int bh = bb * 16 + hh;
    const int nbase = (bm & 2047) + wm;
    float wl[4];
#pragma unroll
    for (int ni = 0; ni < 4; ni++) wl[ni] = w[ni * 16 + col];

#pragma unroll
    for (int mi = 0; mi < 4; mi++) {
#pragma unroll
      for (int r = 0; r < 4; r++) {
        float ssq = 0.0f;
#pragma unroll
        for (int ni = 0; ni < 4; ni++) ssq += acc[mi][ni][r] * acc[mi][ni][r];
        ssq += __shfl_xor(ssq, 1);
        ssq += __shfl_xor(ssq, 2);
        ssq += __shfl_xor(ssq, 4);
        ssq += __shfl_xor(ssq, 8);
        const float rms = rsqrtf(ssq * (1.0f / 64.0f) + 1e-6f);
        const int n = nbase + mi * 16 + quad * 4 + r;
        u16* orow = Out + ((size_t)bh * 2048 + n) * 64;
#pragma unroll
        for (int ni = 0; ni < 4; ni++) {
          const int d = ni * 16 + col;
          float v = acc[mi][ni][r] * rms * wl[ni];
          const float cc = pcos[n * 32 + (d >> 1)];
          const float ss = psin[n * 32 + (d >> 1)];
          const float vp = __shfl_xor(v, 1);
          float o = (col & 1) ? (vp * ss + v * cc) : (v * cc - vp * ss);
          if (region == 0) o *= QSCALE;
          orow[d] = f2bf(o);
        }
      }
    }
  }
}

// ---------------------------------------------------------------------------
// NT GEMM (proj): C[M,N] = A[M,K] @ B[N,K]^T, 64x128 tiles (MT=2) -> 512
// blocks = 2/CU residency at M=4096,N=1024.
// ---------------------------------------------------------------------------
template <int BIAS, int OUTBF16, int MT>
__global__ __launch_bounds__(256) void gemm_nt(
    const u16* __restrict__ A, const u16* __restrict__ B,
    const float* __restrict__ bias, void* __restrict__ Cout,
    int M, int N, int K) {
  constexpr int ROWS_A = MT * 32;
  __shared__ u16 As[ROWS_A * 32];
  __shared__ u16 Bs[128 * 32];
  const int tid = threadIdx.x;
  const int lane = tid & 63;
  const int wave = tid >> 6;
  const int col = lane & 15;
  const int quad = lane >> 4;
  const int bm = blockIdx.y * ROWS_A;
  const int bn = blockIdx.x * 128;
  const int wm = (wave >> 1) * (MT * 16);
  const int wn = (wave & 1) * 64;

  floatx4 acc[MT][4] = {};

  for (int kb = 0; kb < K; kb += 32) {
    __syncthreads();
#pragma unroll
    for (int c = tid; c < ROWS_A * 4; c += 256)
      gl_lds16(A + (size_t)(bm + (c >> 2)) * K + kb + (c & 3) * 8, As + c * 8);
#pragma unroll
    for (int c = tid; c < 512; c += 256)
      gl_lds16(B + (size_t)(bn + (c >> 2)) * K + kb + (c & 3) * 8, Bs + c * 8);
    __syncthreads();

    short8 af[MT], bfr[4];
#pragma unroll
    for (int i = 0; i < MT; i++)
      af[i] = *(const short8*)(As + (wm + i * 16 + col) * 32 + quad * 8);
#pragma unroll
    for (int i = 0; i < 4; i++)
      bfr[i] = *(const short8*)(Bs + (wn + i * 16 + col) * 32 + quad * 8);
#pragma unroll
    for (int mi = 0; mi < MT; mi++)
#pragma unroll
      for (int ni = 0; ni < 4; ni++)
        acc[mi][ni] = __builtin_amdgcn_mfma_f32_16x16x32_bf16(
            af[mi], bfr[ni], acc[mi][ni], 0, 0, 0);
  }

#pragma unroll
  for (int mi = 0; mi < MT; mi++) {
#pragma unroll
    for (int ni = 0; ni < 4; ni++) {
#pragma unroll
      for (int r = 0; r < 4; r++) {
        int row = bm + wm + mi * 16 + quad * 4 + r;
        int c = bn + wn + ni * 16 + col;
        float v = acc[mi][ni][r];
        if (BIAS) v += bias[c];
        if (OUTBF16)
          ((u16*)Cout)[(size_t)row * N + c] = f2bf(v);
        else
          ((float*)Cout)[(size_t)row * N + c] = v;
      }
    }
  }
}

// ---------------------------------------------------------------------------
// V transpose: Vraw [token][1024] -> Vt [bh][d][n], 64x64 LDS tiles,
// coalesced 128B rows both directions.
// ---------------------------------------------------------------------------
__global__ __launch_bounds__(256) void vtrans(const u16* __restrict__ Vraw,
                                              u16* __restrict__ Vt) {
  __shared__ u16 T[64 * 68];
  const int bh = blockIdx.x;  // b*16+h
  const int n0 = blockIdx.y * 64;
  const int b = bh >> 4, h = bh & 15;
  const int tid = threadIdx.x;
  const int q = tid & 7;   // 16B chunk within a 128B row
  const int r = tid >> 3;  // 0..31

#pragma unroll
  for (int rr = r; rr < 64; rr += 32) {
    short8 v = *(const short8*)(Vraw + (size_t)(b * 2048 + n0 + rr) * 1024 +
                                h * 64 + q * 8);
    *(short8*)&T[rr * 68 + q * 8] = v;
  }
  __syncthreads();
#pragma unroll
  for (int dd = r; dd < 64; dd += 32) {
    short8 o;
#pragma unroll
    for (int j = 0; j < 8; j++) o[j] = T[(q * 8 + j) * 68 + dd];
    *(short8*)(Vt + (size_t)(bh * 64 + dd) * 2048 + n0 + q * 8) = o;
  }
}

// ---------------------------------------------------------------------------
// Flash attention v9 (causal) — unchanged from round 9 (measured best).
// ---------------------------------------------------------------------------
#define PSTR 68
__global__ __launch_bounds__(256) void attn_flash(
    const u16* __restrict__ Q, const u16* __restrict__ Kk,
    const u16* __restrict__ Vt, u16* __restrict__ O) {
  __shared__ u16 Ks[2][64 * 32];    // [d-half][key][32d]
  __shared__ u16 Vs[2][64 * 32];    // [key-half][d][32keys]
  __shared__ u16 Pb[4][16 * PSTR];  // per-wave P, [q][key]
  const int id = blockIdx.x;
  const int bh = id & 31;
  const int tile = 31 - (id >> 5);  // big tiles dispatch first
  const int tid = threadIdx.x;
  const int lane = tid & 63;
  const int wave = tid >> 6;
  const int col = lane & 15;
  const int quad = lane >> 4;
  const int srow = tid >> 2;      // staging: row 0..63
  const int spc = (tid & 3) * 8;  // staging: 16B piece

  const u16* Qh = Q + (size_t)bh * 2048 * 64;
  const u16* Kh = Kk + (size_t)bh * 2048 * 64;
  const u16* Vh = Vt + (size_t)bh * 64 * 2048;
  const int b = bh >> 4, h = bh & 15;

  const int q0 = tile * 64 + wave * 16;  // this wave's 16 q-rows

  short8 aq[2];
#pragma unroll
  for (int ks = 0; ks < 2; ks++)
    aq[ks] = *(const short8*)(Qh + (size_t)(q0 + col) * 64 + ks * 32 + quad * 8);

  floatx4 accO[4] = {};
  float ll = 0.0f;  // row-sum for q = q0+col over this lane's keys
  const int nsteps = tile + 1;

  for (int kt = 0; kt < nsteps; kt++) {
    const int j0 = kt * 64;
    __syncthreads();  // prior step's K/V reads done (all waves)
#pragma unroll
    for (int half = 0; half < 2; half++) {
      gl_lds16(Kh + (size_t)(j0 + srow) * 64 + half * 32 + spc,
               &Ks[half][0] + tid * 8);
      gl_lds16(Vh + (size_t)srow * 2048 + j0 + half * 32 + spc,
               &Vs[half][0] + tid * 8);
    }
    __syncthreads();  // fills visible

    // S^T = K Q^T : s[nt][r] = S^T[key=j0+nt*16+quad*4+r][q=q0+col]
    floatx4 s[4] = {};
#pragma unroll
    for (int nt = 0; nt < 4; nt++) {
#pragma unroll
      for (int ks = 0; ks < 2; ks++) {
        short8 bk = *(const short8*)&Ks[ks][(nt * 16 + col) * 32 + quad * 8];
        s[nt] =
            __builtin_amdgcn_mfma_f32_16x16x32_bf16(bk, aq[ks], s[nt], 0, 0, 0);
      }
    }

    // p = exp2(s - bias); mask only on diagonal step; packed b64 P write
    if (j0 + 63 <= q0) {  // fully unmasked fast path
#pragma unroll
      for (int nt = 0; nt < 4; nt++) {
        short4v pk;
#pragma unroll
        for (int r = 0; r < 4; r++) {
          float pv = exp2f(s[nt][r] - EXPBIAS);
          ll += pv;
          pk[r] = (short)f2bf_rtz(pv);
        }
        *(short4v*)&Pb[wave][col * PSTR + nt * 16 + quad * 4] = pk;
      }
    } else {  // diagonal-adjacent: per-key causal mask
      const int qg = q0 + col;
#pragma unroll
      for (int nt = 0; nt < 4; nt++) {
        const int jgb = j0 + nt * 16 + quad * 4;
        short4v pk;
#pragma unroll
        for (int r = 0; r < 4; r++) {
          float pv = (jgb + r <= qg) ? exp2f(s[nt][r] - EXPBIAS) : 0.0f;
          ll += pv;
          pk[r] = (short)f2bf_rtz(pv);
        }
        *(short4v*)&Pb[wave][col * PSTR + nt * 16 + quad * 4] = pk;
      }
    }
    // no barrier: Pb[wave] is wave-private, lgkmcnt orders write->read

    short8 ap[2];
#pragma unroll
    for (int kf = 0; kf < 2; kf++)
      ap[kf] = *(const short8*)&Pb[wave][col * PSTR + kf * 32 + quad * 8];
#pragma unroll
    for (int nt = 0; nt < 4; nt++) {
#pragma unroll
      for (int kf = 0; kf < 2; kf++) {
        short8 bv = *(const short8*)&Vs[kf][(nt * 16 + col) * 32 + quad * 8];
        accO[nt] =
            __builtin_amdgcn_mfma_f32_16x16x32_bf16(ap[kf], bv, accO[nt], 0, 0, 0);
      }
    }
  }

  // total l for q=q0+col: sum the 4 quads, then redistribute for epilogue
  ll += __shfl_xor(ll, 16);
  ll += __shfl_xor(ll, 32);
  float lrec[4];
#pragma unroll
  for (int r = 0; r < 4; r++) lrec[r] = 1.0f / __shfl(ll, quad * 4 + r);

  // epilogue: O token-major [b][n][h][d] feeding the proj GEMM
#pragma unroll
  for (int nt = 0; nt < 4; nt++) {
#pragma unroll
    for (int r = 0; r < 4; r++) {
      int qg = q0 + quad * 4 + r;
      int d = nt * 16 + col;
      O[((size_t)(b * 2048 + qg) * 16 + h) * 64 + d] =
          f2bf(accO[nt][r] * lrec[r]);
    }
  }
}

// ---------------------------------------------------------------------------
extern "C" void kernel_launch(void* const* d_in, const int* in_sizes, int n_in,
                              void* d_out, int out_size, void* d_ws,
                              size_t ws_size, hipStream_t stream) {
  const float* x = (const float*)d_in[0];        // [2,2048,1024] f32
  const float* qkv_w = (const float*)d_in[1];    // [3072,1024] f32
  const float* q_norm_w = (const float*)d_in[2]; // [64] f32
  const float* k_norm_w = (const float*)d_in[3]; // [64] f32
  const float* proj_w = (const float*)d_in[4];   // [1024,1024] f32
  const float* proj_b = (const float*)d_in[5];   // [1024] f32
  const float* pos_cos = (const float*)d_in[6];  // [2048,32] f32
  const float* pos_sin = (const float*)d_in[7];  // [2048,32] f32
  // d_in[8] = causal mask: known analytically, ignored

  char* ws = (char*)d_ws;
  u16* xb = (u16*)ws;                          //  8 MB (4096*1024 bf16)
  u16* wqkvb = (u16*)(ws + 8388608);           //  6 MB (3072*1024 bf16)
  u16* wprojb = (u16*)(ws + 14680064);         //  2 MB (1024*1024 bf16)
  u16* Vraw = (u16*)(ws + 16777216);           //  8 MB (4096*1024 bf16)
  u16* Qb = (u16*)(ws + 25165824);             //  8 MB
  u16* Kb = (u16*)(ws + 33554432);             //  8 MB
  u16* Vt = (u16*)(ws + 41943040);             //  8 MB
  u16* AO = (u16*)(ws + 50331648);             //  8 MB  (total 56 MB)

  // 0) all f32 -> bf16 conversions, one launch
  cvt_all<<<8192, 256, 0, stream>>>(x, qkv_w, proj_w, xb, wqkvb, wprojb);

  // 1) fused qkv GEMM + rmsnorm + rope (Q,K) + compact V emit
  gemm_qkv<<<dim3(24, 32), 256, 0, stream>>>(xb, wqkvb, q_norm_w, k_norm_w,
                                             pos_cos, pos_sin, Qb, Kb, Vraw);

  // 2) V transpose to [bh][d][n]
  vtrans<<<dim3(32, 32), 256, 0, stream>>>(Vraw, Vt);

  // 3) causal flash attention v9: 1024 blocks (64q, 4 waves), big tiles first
  attn_flash<<<dim3(1024), 256, 0, stream>>>(Qb, Kb, Vt, AO);

  // 4) out = AO @ proj_w^T + proj_b: 64x128 tiles -> 512 blocks (2/CU), f32
  gemm_nt<1, 0, 2><<<dim3(8, 64), 256, 0, stream>>>(AO, wprojb, proj_b,
                                                    (float*)d_out, 4096, 1024,
                                                    1024);
}